// Round 1
// baseline (474.531 us; speedup 1.0000x reference)
//
#include <hip/hip_runtime.h>

#define GAS __attribute__((address_space(1)))
#define LAS __attribute__((address_space(3)))

typedef __attribute__((ext_vector_type(8))) short short8;
typedef __attribute__((ext_vector_type(4))) float f32x4;

// ---------- bf16 helpers (manual, header-version-proof) ----------
__device__ __forceinline__ unsigned short f2b(float f) {
  unsigned u = __float_as_uint(f);
  u += 0x7fffu + ((u >> 16) & 1u);          // RNE
  return (unsigned short)(u >> 16);
}
__device__ __forceinline__ float b2f(unsigned short h) {
  return __uint_as_float(((unsigned)h) << 16);
}

// ---------- fp32 -> bf16 bulk convert ----------
__global__ void cvt_f32_bf16(const float* __restrict__ src,
                             unsigned short* __restrict__ dst, int n4) {
  int i = blockIdx.x * blockDim.x + threadIdx.x;
  if (i >= n4) return;
  float4 v = reinterpret_cast<const float4*>(src)[i];
  ushort4 o;
  o.x = f2b(v.x); o.y = f2b(v.y); o.z = f2b(v.z); o.w = f2b(v.w);
  reinterpret_cast<ushort4*>(dst)[i] = o;
}

// ---------- top-3 mask (softmax is monotonic -> top-k of raw scores) ----------
__global__ void topk_bias(const float* __restrict__ band, float* __restrict__ bias) {
  __shared__ float svals[256];
  __shared__ int   sidx[256];
  __shared__ int   chosen[3];
  const int t = threadIdx.x;
  for (int pass = 0; pass < 3; ++pass) {
    float best = -INFINITY; int bi = 1 << 30;
    for (int j = t; j < 2048; j += 256) {
      float v = band[j];
      bool skip = false;
      for (int p2 = 0; p2 < pass; ++p2) skip |= (chosen[p2] == j);
      if (!skip && (v > best || (v == best && j < bi))) { best = v; bi = j; }
    }
    svals[t] = best; sidx[t] = bi;
    __syncthreads();
    for (int s = 128; s > 0; s >>= 1) {
      if (t < s) {
        float v2 = svals[t + s]; int i2 = sidx[t + s];
        if (v2 > svals[t] || (v2 == svals[t] && i2 < sidx[t])) { svals[t] = v2; sidx[t] = i2; }
      }
      __syncthreads();
    }
    if (t == 0) chosen[pass] = sidx[0];
    __syncthreads();
  }
  for (int j = t; j < 2048; j += 256) {
    bool m = (chosen[0] == j) || (chosen[1] == j) || (chosen[2] == j);
    bias[j] = m ? -INFINITY : 0.0f;
  }
}

// ---------- NT GEMM: C[M][N] = A[M][K] * Bw[N][K]^T + bias, bf16 in/out ----------
#define BM 128
#define BN 128
#define BKK 64
__global__ __launch_bounds__(256) void gemm_bt_bias(
    const unsigned short* __restrict__ A,   // [M][K] bf16
    const unsigned short* __restrict__ Bw,  // [N][K] bf16 (row n = output channel)
    const float* __restrict__ bias,         // [N] f32
    unsigned short* __restrict__ C,         // [M][N] bf16
    int M, int N, int Kd)
{
  __shared__ short As[BM][BKK];
  __shared__ short Bs[BN][BKK];
  const int tid = threadIdx.x;
  const int w = tid >> 6, lane = tid & 63;
  const int wm = w >> 1, wn = w & 1;
  const int m0 = blockIdx.x * BM, n0 = blockIdx.y * BN;
  const int rA = lane >> 3, cA = lane & 7;

  const f32x4 fzero = {0.f, 0.f, 0.f, 0.f};
  f32x4 acc[4][4];
  for (int mt = 0; mt < 4; ++mt)
    for (int nt = 0; nt < 4; ++nt) acc[mt][nt] = fzero;

  const int nK = Kd >> 6;
  for (int kt = 0; kt < nK; ++kt) {
    // stage A and B tiles: wave w covers rows [w*32, w*32+32)
    #pragma unroll
    for (int j = 0; j < 4; ++j) {
      int r = w * 32 + j * 8;
      const unsigned short* ga = A + (size_t)(m0 + r + rA) * Kd + kt * BKK + cA * 8;
      __builtin_amdgcn_global_load_lds((const GAS void*)ga, (LAS void*)&As[r][0], 16, 0, 0);
      const unsigned short* gb = Bw + (size_t)(n0 + r + rA) * Kd + kt * BKK + cA * 8;
      __builtin_amdgcn_global_load_lds((const GAS void*)gb, (LAS void*)&Bs[r][0], 16, 0, 0);
    }
    __syncthreads();
    #pragma unroll
    for (int kc = 0; kc < 2; ++kc) {
      short8 a[4], b[4];
      #pragma unroll
      for (int mt = 0; mt < 4; ++mt)
        a[mt] = *reinterpret_cast<const short8*>(
            &As[wm * 64 + mt * 16 + (lane & 15)][kc * 32 + (lane >> 4) * 8]);
      #pragma unroll
      for (int nt = 0; nt < 4; ++nt)
        b[nt] = *reinterpret_cast<const short8*>(
            &Bs[wn * 64 + nt * 16 + (lane & 15)][kc * 32 + (lane >> 4) * 8]);
      #pragma unroll
      for (int mt = 0; mt < 4; ++mt)
        #pragma unroll
        for (int nt = 0; nt < 4; ++nt)
          acc[mt][nt] = __builtin_amdgcn_mfma_f32_16x16x32_bf16(a[mt], b[nt], acc[mt][nt], 0, 0, 0);
    }
    __syncthreads();
  }
  // epilogue: C/D layout col=lane&15, row=(lane>>4)*4+reg
  #pragma unroll
  for (int nt = 0; nt < 4; ++nt) {
    int col = n0 + wn * 64 + nt * 16 + (lane & 15);
    float bv = bias[col];
    #pragma unroll
    for (int mt = 0; mt < 4; ++mt) {
      int rbase = m0 + wm * 64 + mt * 16 + ((lane >> 4) << 2);
      #pragma unroll
      for (int r = 0; r < 4; ++r)
        C[(size_t)(rbase + r) * N + col] = f2b(acc[mt][nt][r] + bv);
    }
  }
}

// ---------- flash attention: 64 q-rows/block, 64-key tiles ----------
// layouts: q/k/v/ctx are [B][L][H][64] bf16. LDS XOR-swizzle: col ^= (row&7)<<3 (shorts)
__global__ __launch_bounds__(256) void attn_kernel(
    const unsigned short* __restrict__ qg,
    const unsigned short* __restrict__ kg,
    const unsigned short* __restrict__ vg,
    const float* __restrict__ bias,
    unsigned short* __restrict__ ctx)
{
  const int qt = blockIdx.x;            // 32 q-tiles
  const int bh = blockIdx.y;            // B*H = 64
  const int bb = bh >> 4, hh = bh & 15;
  const int tid = threadIdx.x, w = tid >> 6, lane = tid & 63;

  __shared__ short Ks[64][64];          // [key][d], swizzled
  __shared__ short Vt[64][64];          // [d][key], swizzled (transposed V)
  __shared__ short Ps[4][16][64];       // per-wave P, [qrow][key], swizzled

  const f32x4 fzero = {0.f, 0.f, 0.f, 0.f};

  // Q fragments: wave handles q-rows [w*16, w*16+16); A-frag row = lane&15
  const int qrow = qt * 64 + w * 16 + (lane & 15);
  const size_t qbase = ((size_t)(bb * 2048 + qrow) * 16 + hh) * 64;
  short8 qf0 = *reinterpret_cast<const short8*>(qg + qbase + (lane >> 4) * 8);
  short8 qf1 = *reinterpret_cast<const short8*>(qg + qbase + 32 + (lane >> 4) * 8);

  f32x4 oacc[4];
  for (int dt = 0; dt < 4; ++dt) oacc[dt] = fzero;
  float mprev[4] = {-INFINITY, -INFINITY, -INFINITY, -INFINITY};
  float lsum[4] = {0.f, 0.f, 0.f, 0.f};

  for (int t = 0; t < 32; ++t) {
    // ---- stage K (row-major) and V (transposed), swizzled ----
    #pragma unroll
    for (int p = 0; p < 2; ++p) {
      int id = p * 256 + tid;           // 0..511 -> 64 rows x 8 chunks
      int r = id >> 3, c = id & 7;
      size_t gidx = ((size_t)(bb * 2048 + t * 64 + r) * 16 + hh) * 64 + c * 8;
      short8 kv = *reinterpret_cast<const short8*>(kg + gidx);
      *reinterpret_cast<short8*>(&Ks[r][(c * 8) ^ ((r & 7) << 3)]) = kv;
      short8 vv = *reinterpret_cast<const short8*>(vg + gidx);
      #pragma unroll
      for (int jj = 0; jj < 8; ++jj) {
        int d_ = c * 8 + jj;
        Vt[d_][r ^ ((d_ & 7) << 3)] = vv[jj];
      }
    }
    float biasv[4];
    #pragma unroll
    for (int ct = 0; ct < 4; ++ct) biasv[ct] = bias[t * 64 + ct * 16 + (lane & 15)];
    __syncthreads();

    // ---- S = (Q K^T)*scale + bias ----
    f32x4 s[4];
    #pragma unroll
    for (int ct = 0; ct < 4; ++ct) {
      int krow = ct * 16 + (lane & 15);
      short8 k0 = *reinterpret_cast<const short8*>(&Ks[krow][((lane >> 4) * 8) ^ ((krow & 7) << 3)]);
      short8 k1 = *reinterpret_cast<const short8*>(&Ks[krow][(32 + (lane >> 4) * 8) ^ ((krow & 7) << 3)]);
      f32x4 a = fzero;
      a = __builtin_amdgcn_mfma_f32_16x16x32_bf16(qf0, k0, a, 0, 0, 0);
      a = __builtin_amdgcn_mfma_f32_16x16x32_bf16(qf1, k1, a, 0, 0, 0);
      s[ct] = a * 0.125f + biasv[ct];
    }

    // ---- online softmax: row r held by 16 lanes (lane>>4 fixed), reduce via shfl_xor ----
    #pragma unroll
    for (int r = 0; r < 4; ++r) {
      float mx = fmaxf(fmaxf(s[0][r], s[1][r]), fmaxf(s[2][r], s[3][r]));
      mx = fmaxf(mx, __shfl_xor(mx, 1));
      mx = fmaxf(mx, __shfl_xor(mx, 2));
      mx = fmaxf(mx, __shfl_xor(mx, 4));
      mx = fmaxf(mx, __shfl_xor(mx, 8));
      float mnew = fmaxf(mprev[r], mx);
      float alpha = __expf(mprev[r] - mnew);
      float rs = 0.f;
      #pragma unroll
      for (int ct = 0; ct < 4; ++ct) {
        float p = __expf(s[ct][r] - mnew);
        s[ct][r] = p;
        rs += p;
      }
      rs += __shfl_xor(rs, 1); rs += __shfl_xor(rs, 2);
      rs += __shfl_xor(rs, 4); rs += __shfl_xor(rs, 8);
      lsum[r] = lsum[r] * alpha + rs;
      mprev[r] = mnew;
      #pragma unroll
      for (int dt = 0; dt < 4; ++dt) oacc[dt][r] *= alpha;
    }

    // ---- P (C-layout) -> LDS (A-layout source), bf16 ----
    #pragma unroll
    for (int ct = 0; ct < 4; ++ct)
      #pragma unroll
      for (int r = 0; r < 4; ++r) {
        int prow = (lane >> 4) * 4 + r;
        int pcol = ct * 16 + (lane & 15);
        Ps[w][prow][pcol ^ ((prow & 7) << 3)] = (short)f2b(s[ct][r]);
      }
    __syncthreads();

    // ---- O += P V ----
    #pragma unroll
    for (int c = 0; c < 2; ++c) {
      int prow = lane & 15;
      short8 pf = *reinterpret_cast<const short8*>(
          &Ps[w][prow][(c * 32 + (lane >> 4) * 8) ^ ((prow & 7) << 3)]);
      #pragma unroll
      for (int dt = 0; dt < 4; ++dt) {
        int vrow = dt * 16 + (lane & 15);
        short8 vf = *reinterpret_cast<const short8*>(
            &Vt[vrow][(c * 32 + (lane >> 4) * 8) ^ ((vrow & 7) << 3)]);
        oacc[dt] = __builtin_amdgcn_mfma_f32_16x16x32_bf16(pf, vf, oacc[dt], 0, 0, 0);
      }
    }
    __syncthreads();
  }

  // ---- epilogue: ctx = O / l ----
  #pragma unroll
  for (int dt = 0; dt < 4; ++dt)
    #pragma unroll
    for (int r = 0; r < 4; ++r) {
      int lrow = qt * 64 + w * 16 + (lane >> 4) * 4 + r;
      int d = dt * 16 + (lane & 15);
      float val = oacc[dt][r] / lsum[r];
      ctx[((size_t)(bb * 2048 + lrow) * 16 + hh) * 64 + d] = (short)f2b(val);
    }
}

// ---------- residual + LayerNorm ----------
__global__ __launch_bounds__(256) void resid_ln(
    const float* __restrict__ x, const unsigned short* __restrict__ ao,
    const float* __restrict__ gamma, const float* __restrict__ beta,
    float* __restrict__ out)
{
  const int row = blockIdx.x, t = threadIdx.x;
  const size_t base = (size_t)row * 1024;
  float4 xv = reinterpret_cast<const float4*>(x + base)[t];
  ushort4 av = reinterpret_cast<const ushort4*>(ao + base)[t];
  float y[4] = {xv.x + b2f(av.x), xv.y + b2f(av.y), xv.z + b2f(av.z), xv.w + b2f(av.w)};
  float sum = y[0] + y[1] + y[2] + y[3];
  float sq = y[0] * y[0] + y[1] * y[1] + y[2] * y[2] + y[3] * y[3];
  #pragma unroll
  for (int off = 1; off < 64; off <<= 1) {
    sum += __shfl_xor(sum, off);
    sq += __shfl_xor(sq, off);
  }
  __shared__ float s1[4], s2[4];
  int w = t >> 6, lane = t & 63;
  if (lane == 0) { s1[w] = sum; s2[w] = sq; }
  __syncthreads();
  sum = s1[0] + s1[1] + s1[2] + s1[3];
  sq = s2[0] + s2[1] + s2[2] + s2[3];
  float mu = sum * (1.f / 1024.f);
  float var = sq * (1.f / 1024.f) - mu * mu;
  float inv = rsqrtf(var + 1e-5f);
  float4 gv = reinterpret_cast<const float4*>(gamma)[t];
  float4 bv = reinterpret_cast<const float4*>(beta)[t];
  float4 o;
  o.x = (y[0] - mu) * inv * gv.x + bv.x;
  o.y = (y[1] - mu) * inv * gv.y + bv.y;
  o.z = (y[2] - mu) * inv * gv.z + bv.z;
  o.w = (y[3] - mu) * inv * gv.w + bv.w;
  reinterpret_cast<float4*>(out + base)[t] = o;
}

// ---------- launch ----------
extern "C" void kernel_launch(void* const* d_in, const int* in_sizes, int n_in,
                              void* d_out, int out_size, void* d_ws, size_t ws_size,
                              hipStream_t stream)
{
  const float* x     = (const float*)d_in[0];
  const float* band  = (const float*)d_in[1];
  const float* Wq    = (const float*)d_in[2];
  const float* bq    = (const float*)d_in[3];
  const float* Wk    = (const float*)d_in[4];
  const float* bk    = (const float*)d_in[5];
  const float* Wv    = (const float*)d_in[6];
  const float* bv    = (const float*)d_in[7];
  const float* Wo    = (const float*)d_in[8];
  const float* bo    = (const float*)d_in[9];
  const float* gamma = (const float*)d_in[10];
  const float* beta  = (const float*)d_in[11];
  float* out = (float*)d_out;

  char* ws = (char*)d_ws;
  float*          biasw = (float*)(ws);                       // 8 KB
  unsigned short* xb    = (unsigned short*)(ws + 8192);       // 16 MB
  unsigned short* Wqb   = (unsigned short*)(ws + 16785408);
  unsigned short* Wkb   = (unsigned short*)(ws + 18882560);
  unsigned short* Wvb   = (unsigned short*)(ws + 20979712);
  unsigned short* Wob   = (unsigned short*)(ws + 23076864);
  unsigned short* qb    = (unsigned short*)(ws + 25174016);
  unsigned short* kb    = (unsigned short*)(ws + 41951232);
  unsigned short* vb    = (unsigned short*)(ws + 58728448);
  unsigned short* ctxb  = (unsigned short*)(ws + 75505664);
  unsigned short* aob   = (unsigned short*)(ws + 92282880);   // end: 109060096

  cvt_f32_bf16<<<8192, 256, 0, stream>>>(x, xb, 2097152);
  cvt_f32_bf16<<<1024, 256, 0, stream>>>(Wq, Wqb, 262144);
  cvt_f32_bf16<<<1024, 256, 0, stream>>>(Wk, Wkb, 262144);
  cvt_f32_bf16<<<1024, 256, 0, stream>>>(Wv, Wvb, 262144);
  cvt_f32_bf16<<<1024, 256, 0, stream>>>(Wo, Wob, 262144);
  topk_bias<<<1, 256, 0, stream>>>(band, biasw);

  gemm_bt_bias<<<dim3(64, 8), 256, 0, stream>>>(xb, Wqb, bq, qb, 8192, 1024, 1024);
  gemm_bt_bias<<<dim3(64, 8), 256, 0, stream>>>(xb, Wkb, bk, kb, 8192, 1024, 1024);
  gemm_bt_bias<<<dim3(64, 8), 256, 0, stream>>>(xb, Wvb, bv, vb, 8192, 1024, 1024);

  attn_kernel<<<dim3(32, 64), 256, 0, stream>>>(qb, kb, vb, biasw, ctxb);

  gemm_bt_bias<<<dim3(64, 8), 256, 0, stream>>>(ctxb, Wob, bo, aob, 8192, 1024, 1024);

  resid_ln<<<8192, 256, 0, stream>>>(x, aob, gamma, beta, out);
}

// Round 2
// 288.328 us; speedup vs baseline: 1.6458x; 1.6458x over previous
//
#include <hip/hip_runtime.h>

#define GAS __attribute__((address_space(1)))
#define LAS __attribute__((address_space(3)))

typedef __attribute__((ext_vector_type(8))) short short8;
typedef __attribute__((ext_vector_type(4))) float f32x4;
typedef __attribute__((ext_vector_type(16))) float f32x16;
typedef __attribute__((ext_vector_type(4))) unsigned int u32x4;

#define MFMA16(a,b,c) __builtin_amdgcn_mfma_f32_16x16x32_bf16(a,b,c,0,0,0)
#define MFMA32(a,b,c) __builtin_amdgcn_mfma_f32_32x32x16_bf16(a,b,c,0,0,0)

// ---------- bf16 helpers ----------
__device__ __forceinline__ unsigned short f2b(float f) {
  unsigned u = __float_as_uint(f);
  u += 0x7fffu + ((u >> 16) & 1u);          // RNE
  return (unsigned short)(u >> 16);
}
__device__ __forceinline__ float b2f(unsigned short h) {
  return __uint_as_float(((unsigned)h) << 16);
}
__device__ __forceinline__ unsigned cvtpk(float a, float b) {
  unsigned r;
  asm("v_cvt_pk_bf16_f32 %0, %1, %2" : "=v"(r) : "v"(a), "v"(b));
  return r;
}
__device__ __forceinline__ void pl32swap(unsigned &x, unsigned &y) {
  auto r = __builtin_amdgcn_permlane32_swap((int)x, (int)y, false, false);
  x = (unsigned)r[0]; y = (unsigned)r[1];
}
__device__ __forceinline__ float xhalf_max(float v) {
  auto r = __builtin_amdgcn_permlane32_swap(__float_as_int(v), __float_as_int(v), false, false);
  return fmaxf(__int_as_float(r[0]), __int_as_float(r[1]));
}
__device__ __forceinline__ float xhalf_sum(float v) {
  auto r = __builtin_amdgcn_permlane32_swap(__float_as_int(v), __float_as_int(v), false, false);
  return __int_as_float(r[0]) + __int_as_float(r[1]);
}

union FW { u32x4 u; short8 s; };

// ---------- fp32 -> bf16 bulk convert ----------
__global__ void cvt_f32_bf16(const float* __restrict__ src,
                             unsigned short* __restrict__ dst, int n4) {
  int i = blockIdx.x * blockDim.x + threadIdx.x;
  if (i >= n4) return;
  float4 v = reinterpret_cast<const float4*>(src)[i];
  ushort4 o;
  o.x = f2b(v.x); o.y = f2b(v.y); o.z = f2b(v.z); o.w = f2b(v.w);
  reinterpret_cast<ushort4*>(dst)[i] = o;
}

// ---------- top-3 indices (softmax monotonic -> top-k of raw scores) ----------
__global__ void topk_idx(const float* __restrict__ band, int* __restrict__ idxout) {
  __shared__ float svals[256];
  __shared__ int   sidx[256];
  __shared__ int   chosen[3];
  const int t = threadIdx.x;
  for (int pass = 0; pass < 3; ++pass) {
    float best = -INFINITY; int bi = 1 << 30;
    for (int j = t; j < 2048; j += 256) {
      float v = band[j];
      bool skip = false;
      for (int p2 = 0; p2 < pass; ++p2) skip |= (chosen[p2] == j);
      if (!skip && (v > best || (v == best && j < bi))) { best = v; bi = j; }
    }
    svals[t] = best; sidx[t] = bi;
    __syncthreads();
    for (int s = 128; s > 0; s >>= 1) {
      if (t < s) {
        float v2 = svals[t + s]; int i2 = sidx[t + s];
        if (v2 > svals[t] || (v2 == svals[t] && i2 < sidx[t])) { svals[t] = v2; sidx[t] = i2; }
      }
      __syncthreads();
    }
    if (t == 0) chosen[pass] = sidx[0];
    __syncthreads();
  }
  if (t < 3) idxout[t] = chosen[t];
}

// ---------- NT GEMM: C = A * Bw^T + bias, bf16 in/out ----------
// MODE 0: token-major C[M][N];  MODE 1: head-major out[((b*16+h)*2048+l)*64+d]
template<int MODE>
__global__ __launch_bounds__(256) void gemm_bt_bias(
    const unsigned short* __restrict__ A,   // [M][K] bf16
    const unsigned short* __restrict__ Bw,  // [N][K] bf16
    const float* __restrict__ bias,         // [N] f32
    unsigned short* __restrict__ C,
    int M, int N, int Kd)
{
  __shared__ short As[128][64];
  __shared__ short Bs[128][64];
  const int tid = threadIdx.x;
  const int w = tid >> 6, lane = tid & 63;
  const int wm = w >> 1, wn = w & 1;
  const int m0 = blockIdx.x * 128, n0 = blockIdx.y * 128;
  const int rA = lane >> 3, cA = lane & 7;

  f32x4 acc[4][4];
  #pragma unroll
  for (int mt = 0; mt < 4; ++mt)
    #pragma unroll
    for (int nt = 0; nt < 4; ++nt)
      #pragma unroll
      for (int r = 0; r < 4; ++r) acc[mt][nt][r] = 0.f;

  const int nK = Kd >> 6;
  for (int kt = 0; kt < nK; ++kt) {
    #pragma unroll
    for (int j = 0; j < 4; ++j) {
      int r = w * 32 + j * 8;
      const unsigned short* ga = A + (size_t)(m0 + r + rA) * Kd + kt * 64 + cA * 8;
      __builtin_amdgcn_global_load_lds((const GAS void*)ga, (LAS void*)&As[r][0], 16, 0, 0);
      const unsigned short* gb = Bw + (size_t)(n0 + r + rA) * Kd + kt * 64 + cA * 8;
      __builtin_amdgcn_global_load_lds((const GAS void*)gb, (LAS void*)&Bs[r][0], 16, 0, 0);
    }
    __syncthreads();
    #pragma unroll
    for (int kc = 0; kc < 2; ++kc) {
      short8 a[4], b[4];
      #pragma unroll
      for (int mt = 0; mt < 4; ++mt)
        a[mt] = *reinterpret_cast<const short8*>(
            &As[wm * 64 + mt * 16 + (lane & 15)][kc * 32 + (lane >> 4) * 8]);
      #pragma unroll
      for (int nt = 0; nt < 4; ++nt)
        b[nt] = *reinterpret_cast<const short8*>(
            &Bs[wn * 64 + nt * 16 + (lane & 15)][kc * 32 + (lane >> 4) * 8]);
      #pragma unroll
      for (int mt = 0; mt < 4; ++mt)
        #pragma unroll
        for (int nt = 0; nt < 4; ++nt)
          acc[mt][nt] = MFMA16(a[mt], b[nt], acc[mt][nt]);
    }
    __syncthreads();
  }
  #pragma unroll
  for (int nt = 0; nt < 4; ++nt) {
    int col = n0 + wn * 64 + nt * 16 + (lane & 15);
    float bv = bias[col];
    int h_ = col >> 6, d_ = col & 63;
    #pragma unroll
    for (int mt = 0; mt < 4; ++mt) {
      int rbase = m0 + wm * 64 + mt * 16 + ((lane >> 4) << 2);
      #pragma unroll
      for (int r = 0; r < 4; ++r) {
        unsigned short val = f2b(acc[mt][nt][r] + bv);
        if (MODE == 0) {
          C[(size_t)(rbase + r) * N + col] = val;
        } else {
          int row = rbase + r;
          int b_ = row >> 11, lt_ = row & 2047;
          C[(((size_t)(b_ * 16 + h_)) * 2048 + lt_) * 64 + d_] = val;
        }
      }
    }
  }
}

// ---------- V head-major [BH][L][64] -> V^T [BH][64][L] ----------
__global__ __launch_bounds__(256) void transpose_v(
    const unsigned short* __restrict__ vin,
    unsigned short* __restrict__ vout)
{
  __shared__ short T[64 * 64];
  const int lt = blockIdx.x, bh = blockIdx.y;
  const int tid = threadIdx.x;
  #pragma unroll
  for (int p = 0; p < 2; ++p) {
    int id = p * 256 + tid; int l = id >> 3, c = id & 7;
    short8 v = *reinterpret_cast<const short8*>(
        vin + ((size_t)bh * 2048 + lt * 64 + l) * 64 + c * 8);
    *reinterpret_cast<short8*>(&T[l * 64 + ((c ^ (l & 7)) * 8)]) = v;
  }
  __syncthreads();
  #pragma unroll
  for (int p = 0; p < 2; ++p) {
    int id = p * 256 + tid; int d = id >> 3, c2 = id & 7;
    short8 o;
    #pragma unroll
    for (int j = 0; j < 8; ++j) {
      int l = c2 * 8 + j;
      o[j] = T[l * 64 + (((d >> 3) ^ (l & 7)) * 8) + (d & 7)];
    }
    *reinterpret_cast<short8*>(vout + ((size_t)bh * 64 + d) * 2048 + lt * 64 + c2 * 8) = o;
  }
}

// ---------- flash attention, 8-wave swapped-QK 32x32 structure ----------
// q/k head-major [BH][2048][64]; vt [BH][64][2048]; ctx token-major [B][L][H][64]
#define PACK8(S, j0, OUT) {                                        \
    unsigned A_ = cvtpk(S[(j0)+0], S[(j0)+1]);                     \
    unsigned B_ = cvtpk(S[(j0)+4], S[(j0)+5]);                     \
    unsigned C_ = cvtpk(S[(j0)+2], S[(j0)+3]);                     \
    unsigned D_ = cvtpk(S[(j0)+6], S[(j0)+7]);                     \
    pl32swap(A_, B_); pl32swap(C_, D_);                            \
    FW f_; f_.u[0] = A_; f_.u[1] = C_; f_.u[2] = B_; f_.u[3] = D_; \
    OUT = f_.s; }

__global__ __launch_bounds__(512) void attn2(
    const unsigned short* __restrict__ qg,
    const unsigned short* __restrict__ kg,
    const unsigned short* __restrict__ vtg,
    const int* __restrict__ midx,
    unsigned short* __restrict__ ctx)
{
  __shared__ short Ks[2][64 * 64];
  __shared__ short Vs[2][64 * 64];
  const int tid = threadIdx.x, w = tid >> 6, lane = tid & 63;
  const int bh = blockIdx.y;
  const int q0 = blockIdx.x * 256;
  const int lo5 = lane & 31, hi = lane >> 5;
  const int i0 = midx[0], i1 = midx[1], i2 = midx[2];
  const float SCALE = 0.125f;

  // Q fragments (B-operand): lane holds Q[q=q0+w*32+lo5][ds*16 + hi*8 .. +7]
  const int qrow = q0 + w * 32 + lo5;
  const unsigned short* qp = qg + ((size_t)bh * 2048 + qrow) * 64 + hi * 8;
  short8 qf[4];
  #pragma unroll
  for (int ds = 0; ds < 4; ++ds) qf[ds] = *reinterpret_cast<const short8*>(qp + ds * 16);

  f32x16 oacc0, oacc1;
  #pragma unroll
  for (int r = 0; r < 16; ++r) { oacc0[r] = 0.f; oacc1[r] = 0.f; }
  float m = -1e30f, lsum = 0.f;

  // staging geometry: wave w stages rows 8w..8w+7 (K keys / V^T d-rows)
  const int srow = w * 8 + (lane >> 3);
  const int sc = lane & 7;
  const int swz = ((sc ^ (srow & 7)) * 8);
  const unsigned short* kgb = kg + ((size_t)bh * 2048) * 64;
  const unsigned short* vgb = vtg + ((size_t)bh * 64 + srow) * 2048;

#define STAGE(bufi, tt) {                                                     \
    const unsigned short* ksrc = kgb + ((size_t)((tt) * 64 + srow)) * 64 + swz; \
    __builtin_amdgcn_global_load_lds((const GAS void*)ksrc,                   \
        (LAS void*)&Ks[bufi][w * 512], 16, 0, 0);                             \
    const unsigned short* vsrc = vgb + (tt) * 64 + swz;                       \
    __builtin_amdgcn_global_load_lds((const GAS void*)vsrc,                   \
        (LAS void*)&Vs[bufi][w * 512], 16, 0, 0);                             \
  }

  STAGE(0, 0);
  __syncthreads();
  int buf = 0;

  for (int t = 0; t < 32; ++t) {
    if (t < 31) STAGE(buf ^ 1, t + 1);

    // ---- S^T = K · Q^T  (rows k, cols q) ----
    f32x16 s0, s1;
    #pragma unroll
    for (int r = 0; r < 16; ++r) { s0[r] = 0.f; s1[r] = 0.f; }
    #pragma unroll
    for (int ds = 0; ds < 4; ++ds) {
      int cw = ds * 2 + hi;
      short8 k0 = *reinterpret_cast<const short8*>(
          &Ks[buf][lo5 * 64 + ((cw ^ (lo5 & 7)) * 8)]);
      short8 k1 = *reinterpret_cast<const short8*>(
          &Ks[buf][(32 + lo5) * 64 + ((cw ^ (lo5 & 7)) * 8)]);
      s0 = MFMA32(k0, qf[ds], s0);
      s1 = MFMA32(k1, qf[ds], s1);
    }

    // ---- online softmax (per-lane q) ----
    float tmax = s0[0];
    #pragma unroll
    for (int r = 1; r < 16; ++r) tmax = fmaxf(tmax, s0[r]);
    #pragma unroll
    for (int r = 0; r < 16; ++r) tmax = fmaxf(tmax, s1[r]);
    tmax = xhalf_max(tmax);
    float msc = tmax * SCALE;

    if (!__all(msc <= m + 8.0f)) {     // defer-max (T13): rescale only on growth
      float mnew = fmaxf(m, msc);
      float alpha = __expf(m - mnew);
      #pragma unroll
      for (int r = 0; r < 16; ++r) {
        int row = (r & 3) + 8 * (r >> 2) + 4 * hi;
        float ar = __int_as_float(__builtin_amdgcn_ds_bpermute(
            (row + (lane & 32)) * 4, __float_as_int(alpha)));
        oacc0[r] *= ar; oacc1[r] *= ar;
      }
      lsum *= alpha;
      m = mnew;
    }
    float negm = -m;
    #pragma unroll
    for (int r = 0; r < 16; ++r) s0[r] = __expf(fmaf(s0[r], SCALE, negm));
    #pragma unroll
    for (int r = 0; r < 16; ++r) s1[r] = __expf(fmaf(s1[r], SCALE, negm));

    // ---- zero masked columns (rare tiles; uniform branch) ----
    int t64 = t * 64;
    bool tm = ((unsigned)(i0 - t64) < 64u) | ((unsigned)(i1 - t64) < 64u) |
              ((unsigned)(i2 - t64) < 64u);
    if (tm) {
      #pragma unroll
      for (int r = 0; r < 16; ++r) {
        int kg0 = t64 + (r & 3) + 8 * (r >> 2) + 4 * hi;
        int kg1 = kg0 + 32;
        if (kg0 == i0 || kg0 == i1 || kg0 == i2) s0[r] = 0.f;
        if (kg1 == i0 || kg1 == i1 || kg1 == i2) s1[r] = 0.f;
      }
    }

    float rsum = 0.f;
    #pragma unroll
    for (int r = 0; r < 16; ++r) rsum += s0[r] + s1[r];
    rsum = xhalf_sum(rsum);
    lsum += rsum;

    // ---- P -> bf16 A-frags in-register (16 cvt_pk + 8 permlane32_swap) ----
    short8 pa[4];
    PACK8(s0, 0, pa[0]); PACK8(s0, 8, pa[1]);
    PACK8(s1, 0, pa[2]); PACK8(s1, 8, pa[3]);

    // ---- O += P · V ----
    #pragma unroll
    for (int ks = 0; ks < 4; ++ks) {
      int cw = ks * 2 + hi;
      short8 v0 = *reinterpret_cast<const short8*>(
          &Vs[buf][lo5 * 64 + ((cw ^ (lo5 & 7)) * 8)]);
      short8 v1 = *reinterpret_cast<const short8*>(
          &Vs[buf][(32 + lo5) * 64 + ((cw ^ (lo5 & 7)) * 8)]);
      oacc0 = MFMA32(pa[ks], v0, oacc0);
      oacc1 = MFMA32(pa[ks], v1, oacc1);
    }
    __syncthreads();
    buf ^= 1;
  }

  // ---- epilogue: ctx = O / lsum, token-major ----
  const int bb = bh >> 4, hh = bh & 15;
  float rinv = 1.0f / lsum;
  #pragma unroll
  for (int r = 0; r < 16; ++r) {
    int row = (r & 3) + 8 * (r >> 2) + 4 * hi;
    float rv = __int_as_float(__builtin_amdgcn_ds_bpermute(
        (row + (lane & 32)) * 4, __float_as_int(rinv)));
    int qr = q0 + w * 32 + row;
    size_t base = (((size_t)(bb * 2048 + qr)) * 16 + hh) * 64;
    ctx[base + lo5]      = f2b(oacc0[r] * rv);
    ctx[base + 32 + lo5] = f2b(oacc1[r] * rv);
  }
}

// ---------- residual + LayerNorm ----------
__global__ __launch_bounds__(256) void resid_ln(
    const float* __restrict__ x, const unsigned short* __restrict__ ao,
    const float* __restrict__ gamma, const float* __restrict__ beta,
    float* __restrict__ out)
{
  const int row = blockIdx.x, t = threadIdx.x;
  const size_t base = (size_t)row * 1024;
  float4 xv = reinterpret_cast<const float4*>(x + base)[t];
  ushort4 av = reinterpret_cast<const ushort4*>(ao + base)[t];
  float y[4] = {xv.x + b2f(av.x), xv.y + b2f(av.y), xv.z + b2f(av.z), xv.w + b2f(av.w)};
  float sum = y[0] + y[1] + y[2] + y[3];
  float sq = y[0] * y[0] + y[1] * y[1] + y[2] * y[2] + y[3] * y[3];
  #pragma unroll
  for (int off = 1; off < 64; off <<= 1) {
    sum += __shfl_xor(sum, off);
    sq += __shfl_xor(sq, off);
  }
  __shared__ float s1[4], s2[4];
  int w = t >> 6, lane = t & 63;
  if (lane == 0) { s1[w] = sum; s2[w] = sq; }
  __syncthreads();
  sum = s1[0] + s1[1] + s1[2] + s1[3];
  sq = s2[0] + s2[1] + s2[2] + s2[3];
  float mu = sum * (1.f / 1024.f);
  float var = sq * (1.f / 1024.f) - mu * mu;
  float inv = rsqrtf(var + 1e-5f);
  float4 gv = reinterpret_cast<const float4*>(gamma)[t];
  float4 bv = reinterpret_cast<const float4*>(beta)[t];
  float4 o;
  o.x = (y[0] - mu) * inv * gv.x + bv.x;
  o.y = (y[1] - mu) * inv * gv.y + bv.y;
  o.z = (y[2] - mu) * inv * gv.z + bv.z;
  o.w = (y[3] - mu) * inv * gv.w + bv.w;
  reinterpret_cast<float4*>(out + base)[t] = o;
}

// ---------- launch ----------
extern "C" void kernel_launch(void* const* d_in, const int* in_sizes, int n_in,
                              void* d_out, int out_size, void* d_ws, size_t ws_size,
                              hipStream_t stream)
{
  const float* x     = (const float*)d_in[0];
  const float* band  = (const float*)d_in[1];
  const float* Wq    = (const float*)d_in[2];
  const float* bq    = (const float*)d_in[3];
  const float* Wk    = (const float*)d_in[4];
  const float* bk    = (const float*)d_in[5];
  const float* Wv    = (const float*)d_in[6];
  const float* bv    = (const float*)d_in[7];
  const float* Wo    = (const float*)d_in[8];
  const float* bo    = (const float*)d_in[9];
  const float* gamma = (const float*)d_in[10];
  const float* beta  = (const float*)d_in[11];
  float* out = (float*)d_out;

  char* ws = (char*)d_ws;
  int*            idxw = (int*)(ws);                          // 3 ints
  unsigned short* xb   = (unsigned short*)(ws + 4096);        // 16 MB
  unsigned short* Wqb  = (unsigned short*)(ws + 16781312);
  unsigned short* Wkb  = (unsigned short*)(ws + 18878464);
  unsigned short* Wvb  = (unsigned short*)(ws + 20975616);
  unsigned short* Wob  = (unsigned short*)(ws + 23072768);
  unsigned short* qb   = (unsigned short*)(ws + 25169920);    // head-major
  unsigned short* kb   = (unsigned short*)(ws + 41947136);    // head-major
  unsigned short* vhb  = (unsigned short*)(ws + 58724352);    // head-major V
  unsigned short* vtb  = (unsigned short*)(ws + 75501568);    // V^T [BH][64][L]
  unsigned short* ctxb = vhb;                                 // reuse after transpose
  unsigned short* aob  = qb;                                  // reuse after attn

  cvt_f32_bf16<<<8192, 256, 0, stream>>>(x, xb, 2097152);
  cvt_f32_bf16<<<1024, 256, 0, stream>>>(Wq, Wqb, 262144);
  cvt_f32_bf16<<<1024, 256, 0, stream>>>(Wk, Wkb, 262144);
  cvt_f32_bf16<<<1024, 256, 0, stream>>>(Wv, Wvb, 262144);
  cvt_f32_bf16<<<1024, 256, 0, stream>>>(Wo, Wob, 262144);
  topk_idx<<<1, 256, 0, stream>>>(band, idxw);

  gemm_bt_bias<1><<<dim3(64, 8), 256, 0, stream>>>(xb, Wqb, bq, qb, 8192, 1024, 1024);
  gemm_bt_bias<1><<<dim3(64, 8), 256, 0, stream>>>(xb, Wkb, bk, kb, 8192, 1024, 1024);
  gemm_bt_bias<1><<<dim3(64, 8), 256, 0, stream>>>(xb, Wvb, bv, vhb, 8192, 1024, 1024);

  transpose_v<<<dim3(32, 64), 256, 0, stream>>>(vhb, vtb);

  attn2<<<dim3(8, 64), 512, 0, stream>>>(qb, kb, vtb, idxw, ctxb);

  gemm_bt_bias<0><<<dim3(64, 8), 256, 0, stream>>>(ctxb, Wob, bo, aob, 8192, 1024, 1024);

  resid_ln<<<8192, 256, 0, stream>>>(x, aob, gamma, beta, out);
}

// Round 3
// 262.085 us; speedup vs baseline: 1.8106x; 1.1001x over previous
//
#include <hip/hip_runtime.h>

#define GAS __attribute__((address_space(1)))
#define LAS __attribute__((address_space(3)))

typedef __attribute__((ext_vector_type(8))) short short8;
typedef __attribute__((ext_vector_type(4))) float f32x4;
typedef __attribute__((ext_vector_type(16))) float f32x16;
typedef __attribute__((ext_vector_type(4))) unsigned int u32x4;

#define MFMA16(a,b,c) __builtin_amdgcn_mfma_f32_16x16x32_bf16(a,b,c,0,0,0)
#define MFMA32(a,b,c) __builtin_amdgcn_mfma_f32_32x32x16_bf16(a,b,c,0,0,0)

// ---------- bf16 helpers ----------
__device__ __forceinline__ unsigned short f2b(float f) {
  unsigned u = __float_as_uint(f);
  u += 0x7fffu + ((u >> 16) & 1u);          // RNE
  return (unsigned short)(u >> 16);
}
__device__ __forceinline__ float b2f(unsigned short h) {
  return __uint_as_float(((unsigned)h) << 16);
}
__device__ __forceinline__ unsigned cvtpk(float a, float b) {
  unsigned r;
  asm("v_cvt_pk_bf16_f32 %0, %1, %2" : "=v"(r) : "v"(a), "v"(b));
  return r;
}
__device__ __forceinline__ void pl32swap(unsigned &x, unsigned &y) {
  auto r = __builtin_amdgcn_permlane32_swap((int)x, (int)y, false, false);
  x = (unsigned)r[0]; y = (unsigned)r[1];
}
__device__ __forceinline__ float xhalf_sum(float v) {
  auto r = __builtin_amdgcn_permlane32_swap(__float_as_int(v), __float_as_int(v), false, false);
  return __int_as_float(r[0]) + __int_as_float(r[1]);
}
__device__ __forceinline__ float fexp2(float x) {
  float r;
  asm("v_exp_f32 %0, %1" : "=v"(r) : "v"(x));   // D = 2^S0
  return r;
}

union FW { u32x4 u; short8 s; };

// ---------- fp32 -> bf16 bulk convert ----------
__global__ void cvt_f32_bf16(const float* __restrict__ src,
                             unsigned short* __restrict__ dst, int n4) {
  int i = blockIdx.x * blockDim.x + threadIdx.x;
  if (i >= n4) return;
  float4 v = reinterpret_cast<const float4*>(src)[i];
  ushort4 o;
  o.x = f2b(v.x); o.y = f2b(v.y); o.z = f2b(v.z); o.w = f2b(v.w);
  reinterpret_cast<ushort4*>(dst)[i] = o;
}

// ---------- top-3 indices (softmax monotonic -> top-k of raw scores) ----------
__global__ void topk_idx(const float* __restrict__ band, int* __restrict__ idxout) {
  __shared__ float svals[256];
  __shared__ int   sidx[256];
  __shared__ int   chosen[3];
  const int t = threadIdx.x;
  for (int pass = 0; pass < 3; ++pass) {
    float best = -INFINITY; int bi = 1 << 30;
    for (int j = t; j < 2048; j += 256) {
      float v = band[j];
      bool skip = false;
      for (int p2 = 0; p2 < pass; ++p2) skip |= (chosen[p2] == j);
      if (!skip && (v > best || (v == best && j < bi))) { best = v; bi = j; }
    }
    svals[t] = best; sidx[t] = bi;
    __syncthreads();
    for (int s = 128; s > 0; s >>= 1) {
      if (t < s) {
        float v2 = svals[t + s]; int i2 = sidx[t + s];
        if (v2 > svals[t] || (v2 == svals[t] && i2 < sidx[t])) { svals[t] = v2; sidx[t] = i2; }
      }
      __syncthreads();
    }
    if (t == 0) chosen[pass] = sidx[0];
    __syncthreads();
  }
  if (t < 3) idxout[t] = chosen[t];
}

// ---------- NT GEMM: C = (A * Bw^T + bias) * scale, bf16 in/out ----------
// MODE 0: token-major C[M][N];  MODE 1: head-major out[((b*16+h)*2048+l)*64+d]
template<int MODE>
__global__ __launch_bounds__(256) void gemm_bt_bias(
    const unsigned short* __restrict__ A,   // [M][K] bf16
    const unsigned short* __restrict__ Bw,  // [N][K] bf16
    const float* __restrict__ bias,         // [N] f32
    unsigned short* __restrict__ C,
    int M, int N, int Kd, float scale)
{
  __shared__ short As[128][64];
  __shared__ short Bs[128][64];
  const int tid = threadIdx.x;
  const int w = tid >> 6, lane = tid & 63;
  const int wm = w >> 1, wn = w & 1;
  // XCD swizzle: one N-panel per XCD
  const int flat = blockIdx.y * gridDim.x + blockIdx.x;
  const int total = gridDim.x * gridDim.y;
  const int cpx = total >> 3;
  const int swb = (flat & 7) * cpx + (flat >> 3);
  const int m0 = (swb % gridDim.x) * 128, n0 = (swb / gridDim.x) * 128;
  const int rA = lane >> 3, cA = lane & 7;

  f32x4 acc[4][4];
  #pragma unroll
  for (int mt = 0; mt < 4; ++mt)
    #pragma unroll
    for (int nt = 0; nt < 4; ++nt)
      #pragma unroll
      for (int r = 0; r < 4; ++r) acc[mt][nt][r] = 0.f;

  const int nK = Kd >> 6;
  for (int kt = 0; kt < nK; ++kt) {
    #pragma unroll
    for (int j = 0; j < 4; ++j) {
      int r = w * 32 + j * 8;
      const unsigned short* ga = A + (size_t)(m0 + r + rA) * Kd + kt * 64 + cA * 8;
      __builtin_amdgcn_global_load_lds((const GAS void*)ga, (LAS void*)&As[r][0], 16, 0, 0);
      const unsigned short* gb = Bw + (size_t)(n0 + r + rA) * Kd + kt * 64 + cA * 8;
      __builtin_amdgcn_global_load_lds((const GAS void*)gb, (LAS void*)&Bs[r][0], 16, 0, 0);
    }
    __syncthreads();
    #pragma unroll
    for (int kc = 0; kc < 2; ++kc) {
      short8 a[4], b[4];
      #pragma unroll
      for (int mt = 0; mt < 4; ++mt)
        a[mt] = *reinterpret_cast<const short8*>(
            &As[wm * 64 + mt * 16 + (lane & 15)][kc * 32 + (lane >> 4) * 8]);
      #pragma unroll
      for (int nt = 0; nt < 4; ++nt)
        b[nt] = *reinterpret_cast<const short8*>(
            &Bs[wn * 64 + nt * 16 + (lane & 15)][kc * 32 + (lane >> 4) * 8]);
      __builtin_amdgcn_s_setprio(1);
      #pragma unroll
      for (int mt = 0; mt < 4; ++mt)
        #pragma unroll
        for (int nt = 0; nt < 4; ++nt)
          acc[mt][nt] = MFMA16(a[mt], b[nt], acc[mt][nt]);
      __builtin_amdgcn_s_setprio(0);
    }
    __syncthreads();
  }
  #pragma unroll
  for (int nt = 0; nt < 4; ++nt) {
    int col = n0 + wn * 64 + nt * 16 + (lane & 15);
    float bv = bias[col];
    int h_ = col >> 6, d_ = col & 63;
    #pragma unroll
    for (int mt = 0; mt < 4; ++mt) {
      int rbase = m0 + wm * 64 + mt * 16 + ((lane >> 4) << 2);
      #pragma unroll
      for (int r = 0; r < 4; ++r) {
        unsigned short val = f2b((acc[mt][nt][r] + bv) * scale);
        if (MODE == 0) {
          C[(size_t)(rbase + r) * N + col] = val;
        } else {
          int row = rbase + r;
          int b_ = row >> 11, lt_ = row & 2047;
          C[(((size_t)(b_ * 16 + h_)) * 2048 + lt_) * 64 + d_] = val;
        }
      }
    }
  }
}

// ---------- V head-major [BH][L][64] -> V^T [BH][64][L] ----------
__global__ __launch_bounds__(256) void transpose_v(
    const unsigned short* __restrict__ vin,
    unsigned short* __restrict__ vout)
{
  __shared__ short T[64 * 64];
  const int lt = blockIdx.x, bh = blockIdx.y;
  const int tid = threadIdx.x;
  #pragma unroll
  for (int p = 0; p < 2; ++p) {
    int id = p * 256 + tid; int l = id >> 3, c = id & 7;
    short8 v = *reinterpret_cast<const short8*>(
        vin + ((size_t)bh * 2048 + lt * 64 + l) * 64 + c * 8);
    *reinterpret_cast<short8*>(&T[l * 64 + ((c ^ (l & 7)) * 8)]) = v;
  }
  __syncthreads();
  #pragma unroll
  for (int p = 0; p < 2; ++p) {
    int id = p * 256 + tid; int d = id >> 3, c2 = id & 7;
    short8 o;
    #pragma unroll
    for (int j = 0; j < 8; ++j) {
      int l = c2 * 8 + j;
      o[j] = T[l * 64 + (((d >> 3) ^ (l & 7)) * 8) + (d & 7)];
    }
    *reinterpret_cast<short8*>(vout + ((size_t)bh * 64 + d) * 2048 + lt * 64 + c2 * 8) = o;
  }
}

// ---------- flash attention, 4-wave swapped-QK, static-max softmax ----------
// qg pre-scaled by 0.125*log2(e); k head-major [BH][2048][64]; vt [BH][64][2048]
#define PACK8(S, j0, OUT) {                                        \
    unsigned A_ = cvtpk(S[(j0)+0], S[(j0)+1]);                     \
    unsigned B_ = cvtpk(S[(j0)+4], S[(j0)+5]);                     \
    unsigned C_ = cvtpk(S[(j0)+2], S[(j0)+3]);                     \
    unsigned D_ = cvtpk(S[(j0)+6], S[(j0)+7]);                     \
    pl32swap(A_, B_); pl32swap(C_, D_);                            \
    FW f_; f_.u[0] = A_; f_.u[1] = C_; f_.u[2] = B_; f_.u[3] = D_; \
    OUT = f_.s; }

__global__ __launch_bounds__(256, 3) void attn3(
    const unsigned short* __restrict__ qg,
    const unsigned short* __restrict__ kg,
    const unsigned short* __restrict__ vtg,
    const int* __restrict__ midx,
    unsigned short* __restrict__ ctx)
{
  __shared__ short Ks[2][64 * 64];
  __shared__ short Vs[2][64 * 64];
  const int tid = threadIdx.x, w = tid >> 6, lane = tid & 63;
  // XCD swizzle: 8 consecutive bh per XCD -> K/V L2-resident
  const int flat = blockIdx.y * 16 + blockIdx.x;
  const int swzb = (flat & 7) * 128 + (flat >> 3);
  const int qt = swzb & 15, bh = swzb >> 4;
  const int q0 = qt * 128;
  const int lo5 = lane & 31, hi = lane >> 5;
  const int i0 = midx[0], i1 = midx[1], i2 = midx[2];

  // Q fragments (B-operand), already scaled by 0.125*log2e
  const int qrow = q0 + w * 32 + lo5;
  const unsigned short* qp = qg + ((size_t)bh * 2048 + qrow) * 64 + hi * 8;
  short8 qf[4];
  #pragma unroll
  for (int ds = 0; ds < 4; ++ds) qf[ds] = *reinterpret_cast<const short8*>(qp + ds * 16);

  f32x16 oacc0, oacc1, lacc;
  #pragma unroll
  for (int r = 0; r < 16; ++r) { oacc0[r] = 0.f; oacc1[r] = 0.f; lacc[r] = 0.f; }

  // staging: per wave, rows [w*8, w*8+8) and [32+w*8, 32+w*8+8)
  const int swzoff = (((lane & 7) ^ (lane >> 3))) * 8;
  const unsigned short* kp0 =
      kg + ((size_t)bh * 2048 + w * 8 + (lane >> 3)) * 64 + swzoff;
  const unsigned short* kp1 = kp0 + 32 * 64;
  const unsigned short* vp0 =
      vtg + ((size_t)(bh * 64 + w * 8 + (lane >> 3))) * 2048 + swzoff;
  const unsigned short* vp1 = vp0 + 32 * 2048;

#define STAGE3(bufi, tt) do {                                                  \
    __builtin_amdgcn_global_load_lds((const GAS void*)(kp0 + (tt) * 4096),     \
        (LAS void*)&Ks[bufi][(w * 8) * 64], 16, 0, 0);                         \
    __builtin_amdgcn_global_load_lds((const GAS void*)(kp1 + (tt) * 4096),     \
        (LAS void*)&Ks[bufi][(32 + w * 8) * 64], 16, 0, 0);                    \
    __builtin_amdgcn_global_load_lds((const GAS void*)(vp0 + (tt) * 64),       \
        (LAS void*)&Vs[bufi][(w * 8) * 64], 16, 0, 0);                         \
    __builtin_amdgcn_global_load_lds((const GAS void*)(vp1 + (tt) * 64),       \
        (LAS void*)&Vs[bufi][(32 + w * 8) * 64], 16, 0, 0);                    \
  } while (0)

  STAGE3(0, 0);
  __syncthreads();
  int buf = 0;

  for (int t = 0; t < 32; ++t) {
    if (t < 31) STAGE3(buf ^ 1, t + 1);

    // ---- S^T = K · Q^T (rows k, cols q); Q pre-scaled ----
    f32x16 s0, s1;
    #pragma unroll
    for (int r = 0; r < 16; ++r) { s0[r] = 0.f; s1[r] = 0.f; }
    __builtin_amdgcn_s_setprio(1);
    #pragma unroll
    for (int ds = 0; ds < 4; ++ds) {
      int cw = ds * 2 + hi;
      short8 k0 = *reinterpret_cast<const short8*>(
          &Ks[buf][lo5 * 64 + ((cw ^ (lo5 & 7)) * 8)]);
      short8 k1 = *reinterpret_cast<const short8*>(
          &Ks[buf][(32 + lo5) * 64 + ((cw ^ (lo5 & 7)) * 8)]);
      s0 = MFMA32(k0, qf[ds], s0);
      s1 = MFMA32(k1, qf[ds], s1);
    }
    __builtin_amdgcn_s_setprio(0);

    // ---- static-max softmax: p = 2^s (scale folded into Q) ----
    #pragma unroll
    for (int r = 0; r < 16; ++r) s0[r] = fexp2(s0[r]);
    #pragma unroll
    for (int r = 0; r < 16; ++r) s1[r] = fexp2(s1[r]);

    // ---- zero masked columns (rare tiles; uniform branch) ----
    int t64 = t * 64;
    bool tm = ((unsigned)(i0 - t64) < 64u) | ((unsigned)(i1 - t64) < 64u) |
              ((unsigned)(i2 - t64) < 64u);
    if (tm) {
      #pragma unroll
      for (int r = 0; r < 16; ++r) {
        int kg0 = t64 + (r & 3) + 8 * (r >> 2) + 4 * hi;
        int kg1 = kg0 + 32;
        if (kg0 == i0 || kg0 == i1 || kg0 == i2) s0[r] = 0.f;
        if (kg1 == i0 || kg1 == i1 || kg1 == i2) s1[r] = 0.f;
      }
    }

    // ---- vector partial row-sums (reduced once at the end) ----
    #pragma unroll
    for (int r = 0; r < 16; ++r) lacc[r] += s0[r] + s1[r];

    // ---- P -> bf16 A-frags in-register ----
    short8 pa[4];
    PACK8(s0, 0, pa[0]); PACK8(s0, 8, pa[1]);
    PACK8(s1, 0, pa[2]); PACK8(s1, 8, pa[3]);

    // ---- O += P · V ----
    __builtin_amdgcn_s_setprio(1);
    #pragma unroll
    for (int ks = 0; ks < 4; ++ks) {
      int cw = ks * 2 + hi;
      short8 v0 = *reinterpret_cast<const short8*>(
          &Vs[buf][lo5 * 64 + ((cw ^ (lo5 & 7)) * 8)]);
      short8 v1 = *reinterpret_cast<const short8*>(
          &Vs[buf][(32 + lo5) * 64 + ((cw ^ (lo5 & 7)) * 8)]);
      oacc0 = MFMA32(pa[ks], v0, oacc0);
      oacc1 = MFMA32(pa[ks], v1, oacc1);
    }
    __builtin_amdgcn_s_setprio(0);
    __syncthreads();
    buf ^= 1;
  }

  // ---- epilogue: ctx = O / lsum, token-major ----
  float lsum = 0.f;
  #pragma unroll
  for (int r = 0; r < 16; ++r) lsum += lacc[r];
  lsum = xhalf_sum(lsum);
  const int bb = bh >> 4, hh = bh & 15;
  float rinv = 1.0f / lsum;
  #pragma unroll
  for (int r = 0; r < 16; ++r) {
    int row = (r & 3) + 8 * (r >> 2) + 4 * hi;
    float rv = __int_as_float(__builtin_amdgcn_ds_bpermute(
        (row + (lane & 32)) * 4, __float_as_int(rinv)));
    int qr = q0 + w * 32 + row;
    size_t base = (((size_t)(bb * 2048 + qr)) * 16 + hh) * 64;
    ctx[base + lo5]      = f2b(oacc0[r] * rv);
    ctx[base + 32 + lo5] = f2b(oacc1[r] * rv);
  }
}

// ---------- residual + LayerNorm ----------
__global__ __launch_bounds__(256) void resid_ln(
    const float* __restrict__ x, const unsigned short* __restrict__ ao,
    const float* __restrict__ gamma, const float* __restrict__ beta,
    float* __restrict__ out)
{
  const int row = blockIdx.x, t = threadIdx.x;
  const size_t base = (size_t)row * 1024;
  float4 xv = reinterpret_cast<const float4*>(x + base)[t];
  ushort4 av = reinterpret_cast<const ushort4*>(ao + base)[t];
  float y[4] = {xv.x + b2f(av.x), xv.y + b2f(av.y), xv.z + b2f(av.z), xv.w + b2f(av.w)};
  float sum = y[0] + y[1] + y[2] + y[3];
  float sq = y[0] * y[0] + y[1] * y[1] + y[2] * y[2] + y[3] * y[3];
  #pragma unroll
  for (int off = 1; off < 64; off <<= 1) {
    sum += __shfl_xor(sum, off);
    sq += __shfl_xor(sq, off);
  }
  __shared__ float s1[4], s2[4];
  int w = t >> 6, lane = t & 63;
  if (lane == 0) { s1[w] = sum; s2[w] = sq; }
  __syncthreads();
  sum = s1[0] + s1[1] + s1[2] + s1[3];
  sq = s2[0] + s2[1] + s2[2] + s2[3];
  float mu = sum * (1.f / 1024.f);
  float var = sq * (1.f / 1024.f) - mu * mu;
  float inv = rsqrtf(var + 1e-5f);
  float4 gv = reinterpret_cast<const float4*>(gamma)[t];
  float4 bv = reinterpret_cast<const float4*>(beta)[t];
  float4 o;
  o.x = (y[0] - mu) * inv * gv.x + bv.x;
  o.y = (y[1] - mu) * inv * gv.y + bv.y;
  o.z = (y[2] - mu) * inv * gv.z + bv.z;
  o.w = (y[3] - mu) * inv * gv.w + bv.w;
  reinterpret_cast<float4*>(out + base)[t] = o;
}

// ---------- launch ----------
extern "C" void kernel_launch(void* const* d_in, const int* in_sizes, int n_in,
                              void* d_out, int out_size, void* d_ws, size_t ws_size,
                              hipStream_t stream)
{
  const float* x     = (const float*)d_in[0];
  const float* band  = (const float*)d_in[1];
  const float* Wq    = (const float*)d_in[2];
  const float* bq    = (const float*)d_in[3];
  const float* Wk    = (const float*)d_in[4];
  const float* bk    = (const float*)d_in[5];
  const float* Wv    = (const float*)d_in[6];
  const float* bv    = (const float*)d_in[7];
  const float* Wo    = (const float*)d_in[8];
  const float* bo    = (const float*)d_in[9];
  const float* gamma = (const float*)d_in[10];
  const float* beta  = (const float*)d_in[11];
  float* out = (float*)d_out;

  char* ws = (char*)d_ws;
  int*            idxw = (int*)(ws);                          // 3 ints
  unsigned short* xb   = (unsigned short*)(ws + 4096);        // 16 MB
  unsigned short* Wqb  = (unsigned short*)(ws + 16781312);
  unsigned short* Wkb  = (unsigned short*)(ws + 18878464);
  unsigned short* Wvb  = (unsigned short*)(ws + 20975616);
  unsigned short* Wob  = (unsigned short*)(ws + 23072768);
  unsigned short* qb   = (unsigned short*)(ws + 25169920);    // head-major, pre-scaled
  unsigned short* kb   = (unsigned short*)(ws + 41947136);    // head-major
  unsigned short* vhb  = (unsigned short*)(ws + 58724352);    // head-major V
  unsigned short* vtb  = (unsigned short*)(ws + 75501568);    // V^T [BH][64][L]
  unsigned short* ctxb = vhb;                                 // reuse after transpose
  unsigned short* aob  = qb;                                  // reuse after attn

  const float QSCALE = 0.125f * 1.44269504f;  // fold softmax scale + log2(e) into Q

  cvt_f32_bf16<<<8192, 256, 0, stream>>>(x, xb, 2097152);
  cvt_f32_bf16<<<1024, 256, 0, stream>>>(Wq, Wqb, 262144);
  cvt_f32_bf16<<<1024, 256, 0, stream>>>(Wk, Wkb, 262144);
  cvt_f32_bf16<<<1024, 256, 0, stream>>>(Wv, Wvb, 262144);
  cvt_f32_bf16<<<1024, 256, 0, stream>>>(Wo, Wob, 262144);
  topk_idx<<<1, 256, 0, stream>>>(band, idxw);

  gemm_bt_bias<1><<<dim3(64, 8), 256, 0, stream>>>(xb, Wqb, bq, qb, 8192, 1024, 1024, QSCALE);
  gemm_bt_bias<1><<<dim3(64, 8), 256, 0, stream>>>(xb, Wkb, bk, kb, 8192, 1024, 1024, 1.0f);
  gemm_bt_bias<1><<<dim3(64, 8), 256, 0, stream>>>(xb, Wvb, bv, vhb, 8192, 1024, 1024, 1.0f);

  transpose_v<<<dim3(32, 64), 256, 0, stream>>>(vhb, vtb);

  attn3<<<dim3(16, 64), 256, 0, stream>>>(qb, kb, vtb, idxw, ctxb);

  gemm_bt_bias<0><<<dim3(64, 8), 256, 0, stream>>>(ctxb, Wob, bo, aob, 8192, 1024, 1024, 1.0f);

  resid_ln<<<8192, 256, 0, stream>>>(x, aob, gamma, beta, out);
}

// Round 4
// 232.428 us; speedup vs baseline: 2.0416x; 1.1276x over previous
//
#include <hip/hip_runtime.h>

#define GAS __attribute__((address_space(1)))
#define LAS __attribute__((address_space(3)))

typedef __attribute__((ext_vector_type(8))) short short8;
typedef __attribute__((ext_vector_type(4))) float f32x4;
typedef __attribute__((ext_vector_type(16))) float f32x16;
typedef __attribute__((ext_vector_type(4))) unsigned int u32x4;

#define MFMA16(a,b,c) __builtin_amdgcn_mfma_f32_16x16x32_bf16(a,b,c,0,0,0)
#define MFMA32(a,b,c) __builtin_amdgcn_mfma_f32_32x32x16_bf16(a,b,c,0,0,0)

// ---------- bf16 helpers ----------
__device__ __forceinline__ unsigned short f2b(float f) {
  unsigned u = __float_as_uint(f);
  u += 0x7fffu + ((u >> 16) & 1u);          // RNE
  return (unsigned short)(u >> 16);
}
__device__ __forceinline__ float b2f(unsigned short h) {
  return __uint_as_float(((unsigned)h) << 16);
}
__device__ __forceinline__ unsigned cvtpk(float a, float b) {
  unsigned r;
  asm("v_cvt_pk_bf16_f32 %0, %1, %2" : "=v"(r) : "v"(a), "v"(b));
  return r;
}
__device__ __forceinline__ void pl32swap(unsigned &x, unsigned &y) {
  auto r = __builtin_amdgcn_permlane32_swap((int)x, (int)y, false, false);
  x = (unsigned)r[0]; y = (unsigned)r[1];
}
__device__ __forceinline__ float xhalf_sum(float v) {
  auto r = __builtin_amdgcn_permlane32_swap(__float_as_int(v), __float_as_int(v), false, false);
  return __int_as_float(r[0]) + __int_as_float(r[1]);
}
__device__ __forceinline__ float fexp2(float x) {
  float r;
  asm("v_exp_f32 %0, %1" : "=v"(r) : "v"(x));   // D = 2^S0
  return r;
}

union FW { u32x4 u; short8 s; };

// ---------- fused fp32 -> bf16 convert: x + Wq/Wk/Wv (packed) + Wo ----------
__global__ void cvt_all(const float* __restrict__ x,
                        const float* __restrict__ Wq, const float* __restrict__ Wk,
                        const float* __restrict__ Wv, const float* __restrict__ Wo,
                        unsigned short* __restrict__ xb,
                        unsigned short* __restrict__ Wqkvb,
                        unsigned short* __restrict__ Wob) {
  const int bid = blockIdx.x;
  const float* src;
  unsigned short* dst;
  int idx;
  if (bid < 8192) {                     // x: 2097152 float4
    src = x; dst = xb; idx = bid * 256 + threadIdx.x;
  } else {                              // weights: 4 x 262144 float4
    int wb = bid - 8192;
    int seg = wb >> 10;
    idx = (wb & 1023) * 256 + threadIdx.x;
    src = (seg == 0) ? Wq : (seg == 1) ? Wk : (seg == 2) ? Wv : Wo;
    dst = (seg == 3) ? Wob : (Wqkvb + (size_t)seg * 1048576);
  }
  float4 v = reinterpret_cast<const float4*>(src)[idx];
  ushort4 o;
  o.x = f2b(v.x); o.y = f2b(v.y); o.z = f2b(v.z); o.w = f2b(v.w);
  reinterpret_cast<ushort4*>(dst)[idx] = o;
}

// ---------- top-3 indices (softmax monotonic -> top-k of raw scores) ----------
__global__ void topk_idx(const float* __restrict__ band, int* __restrict__ idxout) {
  __shared__ float svals[256];
  __shared__ int   sidx[256];
  __shared__ int   chosen[3];
  const int t = threadIdx.x;
  for (int pass = 0; pass < 3; ++pass) {
    float best = -INFINITY; int bi = 1 << 30;
    for (int j = t; j < 2048; j += 256) {
      float v = band[j];
      bool skip = false;
      for (int p2 = 0; p2 < pass; ++p2) skip |= (chosen[p2] == j);
      if (!skip && (v > best || (v == best && j < bi))) { best = v; bi = j; }
    }
    svals[t] = best; sidx[t] = bi;
    __syncthreads();
    for (int s = 128; s > 0; s >>= 1) {
      if (t < s) {
        float v2 = svals[t + s]; int i2 = sidx[t + s];
        if (v2 > svals[t] || (v2 == svals[t] && i2 < sidx[t])) { svals[t] = v2; sidx[t] = i2; }
      }
      __syncthreads();
    }
    if (t == 0) chosen[pass] = sidx[0];
    __syncthreads();
  }
  if (t < 3) idxout[t] = chosen[t];
}

// ---------- fused QKV GEMM: [8192x1024] x [3072x1024]^T, head-major out ----------
// Wqkv rows: 0-1023 = Wq, 1024-2047 = Wk, 2048-3071 = Wv
__global__ __launch_bounds__(256) void gemm_qkv(
    const unsigned short* __restrict__ A,      // [8192][1024]
    const unsigned short* __restrict__ Wqkv,   // [3072][1024]
    const float* __restrict__ bq, const float* __restrict__ bk,
    const float* __restrict__ bv,
    unsigned short* __restrict__ qout, unsigned short* __restrict__ kout,
    unsigned short* __restrict__ vout, float qscale)
{
  __shared__ short As[128][64];
  __shared__ short Bs[128][64];
  const int tid = threadIdx.x;
  const int w = tid >> 6, lane = tid & 63;
  const int wm = w >> 1, wn = w & 1;
  // XCD swizzle (total = 64*24 = 1536, divisible by 8)
  const int flat = blockIdx.y * 64 + blockIdx.x;
  const int swb = (flat & 7) * 192 + (flat >> 3);
  const int m0 = (swb & 63) * 128, n0 = (swb >> 6) * 128;
  const int rA = lane >> 3, cA = lane & 7;

  const int seg = n0 >> 10;
  const float* biasp = (seg == 0) ? bq : (seg == 1) ? bk : bv;
  unsigned short* outp = (seg == 0) ? qout : (seg == 1) ? kout : vout;
  const float scale = (seg == 0) ? qscale : 1.0f;

  f32x4 acc[4][4];
  #pragma unroll
  for (int mt = 0; mt < 4; ++mt)
    #pragma unroll
    for (int nt = 0; nt < 4; ++nt)
      #pragma unroll
      for (int r = 0; r < 4; ++r) acc[mt][nt][r] = 0.f;

  for (int kt = 0; kt < 16; ++kt) {
    #pragma unroll
    for (int j = 0; j < 4; ++j) {
      int r = w * 32 + j * 8;
      const unsigned short* ga = A + (size_t)(m0 + r + rA) * 1024 + kt * 64 + cA * 8;
      __builtin_amdgcn_global_load_lds((const GAS void*)ga, (LAS void*)&As[r][0], 16, 0, 0);
      const unsigned short* gb = Wqkv + (size_t)(n0 + r + rA) * 1024 + kt * 64 + cA * 8;
      __builtin_amdgcn_global_load_lds((const GAS void*)gb, (LAS void*)&Bs[r][0], 16, 0, 0);
    }
    __syncthreads();
    #pragma unroll
    for (int kc = 0; kc < 2; ++kc) {
      short8 a[4], b[4];
      #pragma unroll
      for (int mt = 0; mt < 4; ++mt)
        a[mt] = *reinterpret_cast<const short8*>(
            &As[wm * 64 + mt * 16 + (lane & 15)][kc * 32 + (lane >> 4) * 8]);
      #pragma unroll
      for (int nt = 0; nt < 4; ++nt)
        b[nt] = *reinterpret_cast<const short8*>(
            &Bs[wn * 64 + nt * 16 + (lane & 15)][kc * 32 + (lane >> 4) * 8]);
      __builtin_amdgcn_s_setprio(1);
      #pragma unroll
      for (int mt = 0; mt < 4; ++mt)
        #pragma unroll
        for (int nt = 0; nt < 4; ++nt)
          acc[mt][nt] = MFMA16(a[mt], b[nt], acc[mt][nt]);
      __builtin_amdgcn_s_setprio(0);
    }
    __syncthreads();
  }
  #pragma unroll
  for (int nt = 0; nt < 4; ++nt) {
    int col = n0 + wn * 64 + nt * 16 + (lane & 15);
    int coll = col & 1023;
    float bval = biasp[coll];
    int h_ = coll >> 6, d_ = coll & 63;
    #pragma unroll
    for (int mt = 0; mt < 4; ++mt) {
      int rbase = m0 + wm * 64 + mt * 16 + ((lane >> 4) << 2);
      #pragma unroll
      for (int r = 0; r < 4; ++r) {
        unsigned short val = f2b((acc[mt][nt][r] + bval) * scale);
        int row = rbase + r;
        int b_ = row >> 11, lt_ = row & 2047;
        outp[(((size_t)(b_ * 16 + h_)) * 2048 + lt_) * 64 + d_] = val;
      }
    }
  }
}

// ---------- Wo GEMM: token-major C = A * Wo^T + bo ----------
__global__ __launch_bounds__(256) void gemm_wo(
    const unsigned short* __restrict__ A,   // [8192][1024]
    const unsigned short* __restrict__ Bw,  // [1024][1024]
    const float* __restrict__ bias,
    unsigned short* __restrict__ C)
{
  __shared__ short As[128][64];
  __shared__ short Bs[128][64];
  const int tid = threadIdx.x;
  const int w = tid >> 6, lane = tid & 63;
  const int wm = w >> 1, wn = w & 1;
  const int flat = blockIdx.y * 64 + blockIdx.x;   // total 512
  const int swb = (flat & 7) * 64 + (flat >> 3);
  const int m0 = (swb & 63) * 128, n0 = (swb >> 6) * 128;
  const int rA = lane >> 3, cA = lane & 7;

  f32x4 acc[4][4];
  #pragma unroll
  for (int mt = 0; mt < 4; ++mt)
    #pragma unroll
    for (int nt = 0; nt < 4; ++nt)
      #pragma unroll
      for (int r = 0; r < 4; ++r) acc[mt][nt][r] = 0.f;

  for (int kt = 0; kt < 16; ++kt) {
    #pragma unroll
    for (int j = 0; j < 4; ++j) {
      int r = w * 32 + j * 8;
      const unsigned short* ga = A + (size_t)(m0 + r + rA) * 1024 + kt * 64 + cA * 8;
      __builtin_amdgcn_global_load_lds((const GAS void*)ga, (LAS void*)&As[r][0], 16, 0, 0);
      const unsigned short* gb = Bw + (size_t)(n0 + r + rA) * 1024 + kt * 64 + cA * 8;
      __builtin_amdgcn_global_load_lds((const GAS void*)gb, (LAS void*)&Bs[r][0], 16, 0, 0);
    }
    __syncthreads();
    #pragma unroll
    for (int kc = 0; kc < 2; ++kc) {
      short8 a[4], b[4];
      #pragma unroll
      for (int mt = 0; mt < 4; ++mt)
        a[mt] = *reinterpret_cast<const short8*>(
            &As[wm * 64 + mt * 16 + (lane & 15)][kc * 32 + (lane >> 4) * 8]);
      #pragma unroll
      for (int nt = 0; nt < 4; ++nt)
        b[nt] = *reinterpret_cast<const short8*>(
            &Bs[wn * 64 + nt * 16 + (lane & 15)][kc * 32 + (lane >> 4) * 8]);
      __builtin_amdgcn_s_setprio(1);
      #pragma unroll
      for (int mt = 0; mt < 4; ++mt)
        #pragma unroll
        for (int nt = 0; nt < 4; ++nt)
          acc[mt][nt] = MFMA16(a[mt], b[nt], acc[mt][nt]);
      __builtin_amdgcn_s_setprio(0);
    }
    __syncthreads();
  }
  #pragma unroll
  for (int nt = 0; nt < 4; ++nt) {
    int col = n0 + wn * 64 + nt * 16 + (lane & 15);
    float bval = bias[col];
    #pragma unroll
    for (int mt = 0; mt < 4; ++mt) {
      int rbase = m0 + wm * 64 + mt * 16 + ((lane >> 4) << 2);
      #pragma unroll
      for (int r = 0; r < 4; ++r)
        C[(size_t)(rbase + r) * 1024 + col] = f2b(acc[mt][nt][r] + bval);
    }
  }
}

// ---------- V head-major [BH][L][64] -> V^T [BH][64][L] ----------
__global__ __launch_bounds__(256) void transpose_v(
    const unsigned short* __restrict__ vin,
    unsigned short* __restrict__ vout)
{
  __shared__ short T[64 * 64];
  const int lt = blockIdx.x, bh = blockIdx.y;
  const int tid = threadIdx.x;
  #pragma unroll
  for (int p = 0; p < 2; ++p) {
    int id = p * 256 + tid; int l = id >> 3, c = id & 7;
    short8 v = *reinterpret_cast<const short8*>(
        vin + ((size_t)bh * 2048 + lt * 64 + l) * 64 + c * 8);
    *reinterpret_cast<short8*>(&T[l * 64 + ((c ^ (l & 7)) * 8)]) = v;
  }
  __syncthreads();
  #pragma unroll
  for (int p = 0; p < 2; ++p) {
    int id = p * 256 + tid; int d = id >> 3, c2 = id & 7;
    short8 o;
    #pragma unroll
    for (int j = 0; j < 8; ++j) {
      int l = c2 * 8 + j;
      o[j] = T[l * 64 + (((d >> 3) ^ (l & 7)) * 8) + (d & 7)];
    }
    *reinterpret_cast<short8*>(vout + ((size_t)bh * 64 + d) * 2048 + lt * 64 + c2 * 8) = o;
  }
}

// ---------- flash attention, counted-vmcnt depth-2 pipeline ----------
#define PACK8(S, j0, OUT) {                                        \
    unsigned A_ = cvtpk(S[(j0)+0], S[(j0)+1]);                     \
    unsigned B_ = cvtpk(S[(j0)+4], S[(j0)+5]);                     \
    unsigned C_ = cvtpk(S[(j0)+2], S[(j0)+3]);                     \
    unsigned D_ = cvtpk(S[(j0)+6], S[(j0)+7]);                     \
    pl32swap(A_, B_); pl32swap(C_, D_);                            \
    FW f_; f_.u[0] = A_; f_.u[1] = C_; f_.u[2] = B_; f_.u[3] = D_; \
    OUT = f_.s; }

__global__ __launch_bounds__(256, 3) void attn4(
    const unsigned short* __restrict__ qg,
    const unsigned short* __restrict__ kg,
    const unsigned short* __restrict__ vtg,
    const int* __restrict__ midx,
    unsigned short* __restrict__ ctx)
{
  __shared__ short Ks[2][64 * 64];
  __shared__ short Vs[2][64 * 64];
  const int tid = threadIdx.x, w = tid >> 6, lane = tid & 63;
  // XCD swizzle: 8 consecutive bh per XCD
  const int flat = blockIdx.y * 16 + blockIdx.x;
  const int swzb = (flat & 7) * 128 + (flat >> 3);
  const int qt = swzb & 15, bh = swzb >> 4;
  const int q0 = qt * 128;
  const int lo5 = lane & 31, hi = lane >> 5;
  const int i0 = midx[0], i1 = midx[1], i2 = midx[2];

  const int qrow = q0 + w * 32 + lo5;
  const unsigned short* qp = qg + ((size_t)bh * 2048 + qrow) * 64 + hi * 8;
  short8 qf[4];
  #pragma unroll
  for (int ds = 0; ds < 4; ++ds) qf[ds] = *reinterpret_cast<const short8*>(qp + ds * 16);

  f32x16 oacc0, oacc1, lacc;
  #pragma unroll
  for (int r = 0; r < 16; ++r) { oacc0[r] = 0.f; oacc1[r] = 0.f; lacc[r] = 0.f; }

  const int swzoff = (((lane & 7) ^ (lane >> 3))) * 8;
  const unsigned short* kp0 =
      kg + ((size_t)bh * 2048 + w * 8 + (lane >> 3)) * 64 + swzoff;
  const unsigned short* kp1 = kp0 + 32 * 64;
  const unsigned short* vp0 =
      vtg + ((size_t)(bh * 64 + w * 8 + (lane >> 3))) * 2048 + swzoff;
  const unsigned short* vp1 = vp0 + 32 * 2048;

#define STAGE_K(bufi, tt) do {                                                 \
    __builtin_amdgcn_global_load_lds((const GAS void*)(kp0 + (tt) * 4096),     \
        (LAS void*)&Ks[bufi][(w * 8) * 64], 16, 0, 0);                         \
    __builtin_amdgcn_global_load_lds((const GAS void*)(kp1 + (tt) * 4096),     \
        (LAS void*)&Ks[bufi][(32 + w * 8) * 64], 16, 0, 0);                    \
  } while (0)
#define STAGE_V(bufi, tt) do {                                                 \
    __builtin_amdgcn_global_load_lds((const GAS void*)(vp0 + (tt) * 64),       \
        (LAS void*)&Vs[bufi][(w * 8) * 64], 16, 0, 0);                         \
    __builtin_amdgcn_global_load_lds((const GAS void*)(vp1 + (tt) * 64),       \
        (LAS void*)&Vs[bufi][(32 + w * 8) * 64], 16, 0, 0);                    \
  } while (0)

  // depth-2 prologue: tiles 0 and 1 in flight (8 loads/wave outstanding)
  STAGE_K(0, 0); STAGE_V(0, 0);
  STAGE_K(1, 1); STAGE_V(1, 1);

  for (int t = 0; t < 32; ++t) {
    const int buf = t & 1;
    // wait for tile t's K+V (4 oldest); tile t+1's 4 stay in flight
    if (t < 31) { asm volatile("s_waitcnt vmcnt(4)" ::: "memory"); }
    else        { asm volatile("s_waitcnt vmcnt(0)" ::: "memory"); }
    __builtin_amdgcn_sched_barrier(0);
    __builtin_amdgcn_s_barrier();          // everyone's tile-t data resident
    __builtin_amdgcn_sched_barrier(0);

    // ---- K fragments -> regs ----
    short8 kf[8];
    #pragma unroll
    for (int ds = 0; ds < 4; ++ds) {
      int cw = ds * 2 + hi;
      kf[2 * ds] = *reinterpret_cast<const short8*>(
          &Ks[buf][lo5 * 64 + ((cw ^ (lo5 & 7)) * 8)]);
      kf[2 * ds + 1] = *reinterpret_cast<const short8*>(
          &Ks[buf][(32 + lo5) * 64 + ((cw ^ (lo5 & 7)) * 8)]);
    }
    asm volatile("s_waitcnt lgkmcnt(0)" ::: "memory");
    __builtin_amdgcn_sched_barrier(0);
    __builtin_amdgcn_s_barrier();          // all waves done reading Ks[buf]
    __builtin_amdgcn_sched_barrier(0);
    if (t < 30) STAGE_K(buf, t + 2);       // overwrite Ks[buf] with tile t+2

    // ---- S^T = K · Q^T ----
    f32x16 s0, s1;
    #pragma unroll
    for (int r = 0; r < 16; ++r) { s0[r] = 0.f; s1[r] = 0.f; }
    __builtin_amdgcn_s_setprio(1);
    #pragma unroll
    for (int ds = 0; ds < 4; ++ds) {
      s0 = MFMA32(kf[2 * ds], qf[ds], s0);
      s1 = MFMA32(kf[2 * ds + 1], qf[ds], s1);
    }
    __builtin_amdgcn_s_setprio(0);

    // ---- static-max softmax: p = 2^s ----
    #pragma unroll
    for (int r = 0; r < 16; ++r) s0[r] = fexp2(s0[r]);
    #pragma unroll
    for (int r = 0; r < 16; ++r) s1[r] = fexp2(s1[r]);

    int t64 = t * 64;
    bool tm = ((unsigned)(i0 - t64) < 64u) | ((unsigned)(i1 - t64) < 64u) |
              ((unsigned)(i2 - t64) < 64u);
    if (tm) {
      #pragma unroll
      for (int r = 0; r < 16; ++r) {
        int kg0 = t64 + (r & 3) + 8 * (r >> 2) + 4 * hi;
        int kg1 = kg0 + 32;
        if (kg0 == i0 || kg0 == i1 || kg0 == i2) s0[r] = 0.f;
        if (kg1 == i0 || kg1 == i1 || kg1 == i2) s1[r] = 0.f;
      }
    }

    #pragma unroll
    for (int r = 0; r < 16; ++r) lacc[r] += s0[r] + s1[r];

    short8 pa[4];
    PACK8(s0, 0, pa[0]); PACK8(s0, 8, pa[1]);
    PACK8(s1, 0, pa[2]); PACK8(s1, 8, pa[3]);

    // ---- V fragments -> regs ----
    short8 vf[8];
    #pragma unroll
    for (int ks = 0; ks < 4; ++ks) {
      int cw = ks * 2 + hi;
      vf[2 * ks] = *reinterpret_cast<const short8*>(
          &Vs[buf][lo5 * 64 + ((cw ^ (lo5 & 7)) * 8)]);
      vf[2 * ks + 1] = *reinterpret_cast<const short8*>(
          &Vs[buf][(32 + lo5) * 64 + ((cw ^ (lo5 & 7)) * 8)]);
    }
    asm volatile("s_waitcnt lgkmcnt(0)" ::: "memory");
    __builtin_amdgcn_sched_barrier(0);
    __builtin_amdgcn_s_barrier();          // all waves done reading Vs[buf]
    __builtin_amdgcn_sched_barrier(0);
    if (t < 30) STAGE_V(buf, t + 2);

    // ---- O += P · V ----
    __builtin_amdgcn_s_setprio(1);
    #pragma unroll
    for (int ks = 0; ks < 4; ++ks) {
      oacc0 = MFMA32(pa[ks], vf[2 * ks], oacc0);
      oacc1 = MFMA32(pa[ks], vf[2 * ks + 1], oacc1);
    }
    __builtin_amdgcn_s_setprio(0);
  }

  // ---- epilogue: ctx = O / lsum, token-major ----
  float lsum = 0.f;
  #pragma unroll
  for (int r = 0; r < 16; ++r) lsum += lacc[r];
  lsum = xhalf_sum(lsum);
  const int bb = bh >> 4, hh = bh & 15;
  float rinv = 1.0f / lsum;
  #pragma unroll
  for (int r = 0; r < 16; ++r) {
    int row = (r & 3) + 8 * (r >> 2) + 4 * hi;
    float rv = __int_as_float(__builtin_amdgcn_ds_bpermute(
        (row + (lane & 32)) * 4, __float_as_int(rinv)));
    int qr = q0 + w * 32 + row;
    size_t base = (((size_t)(bb * 2048 + qr)) * 16 + hh) * 64;
    ctx[base + lo5]      = f2b(oacc0[r] * rv);
    ctx[base + 32 + lo5] = f2b(oacc1[r] * rv);
  }
}

// ---------- residual + LayerNorm ----------
__global__ __launch_bounds__(256) void resid_ln(
    const float* __restrict__ x, const unsigned short* __restrict__ ao,
    const float* __restrict__ gamma, const float* __restrict__ beta,
    float* __restrict__ out)
{
  const int row = blockIdx.x, t = threadIdx.x;
  const size_t base = (size_t)row * 1024;
  float4 xv = reinterpret_cast<const float4*>(x + base)[t];
  ushort4 av = reinterpret_cast<const ushort4*>(ao + base)[t];
  float y[4] = {xv.x + b2f(av.x), xv.y + b2f(av.y), xv.z + b2f(av.z), xv.w + b2f(av.w)};
  float sum = y[0] + y[1] + y[2] + y[3];
  float sq = y[0] * y[0] + y[1] * y[1] + y[2] * y[2] + y[3] * y[3];
  #pragma unroll
  for (int off = 1; off < 64; off <<= 1) {
    sum += __shfl_xor(sum, off);
    sq += __shfl_xor(sq, off);
  }
  __shared__ float s1[4], s2[4];
  int w = t >> 6, lane = t & 63;
  if (lane == 0) { s1[w] = sum; s2[w] = sq; }
  __syncthreads();
  sum = s1[0] + s1[1] + s1[2] + s1[3];
  sq = s2[0] + s2[1] + s2[2] + s2[3];
  float mu = sum * (1.f / 1024.f);
  float var = sq * (1.f / 1024.f) - mu * mu;
  float inv = rsqrtf(var + 1e-5f);
  float4 gv = reinterpret_cast<const float4*>(gamma)[t];
  float4 bv = reinterpret_cast<const float4*>(beta)[t];
  float4 o;
  o.x = (y[0] - mu) * inv * gv.x + bv.x;
  o.y = (y[1] - mu) * inv * gv.y + bv.y;
  o.z = (y[2] - mu) * inv * gv.z + bv.z;
  o.w = (y[3] - mu) * inv * gv.w + bv.w;
  reinterpret_cast<float4*>(out + base)[t] = o;
}

// ---------- launch ----------
extern "C" void kernel_launch(void* const* d_in, const int* in_sizes, int n_in,
                              void* d_out, int out_size, void* d_ws, size_t ws_size,
                              hipStream_t stream)
{
  const float* x     = (const float*)d_in[0];
  const float* band  = (const float*)d_in[1];
  const float* Wq    = (const float*)d_in[2];
  const float* bq    = (const float*)d_in[3];
  const float* Wk    = (const float*)d_in[4];
  const float* bk    = (const float*)d_in[5];
  const float* Wv    = (const float*)d_in[6];
  const float* bv    = (const float*)d_in[7];
  const float* Wo    = (const float*)d_in[8];
  const float* bo    = (const float*)d_in[9];
  const float* gamma = (const float*)d_in[10];
  const float* beta  = (const float*)d_in[11];
  float* out = (float*)d_out;

  char* ws = (char*)d_ws;
  int*            idxw  = (int*)(ws);                          // 16 B
  unsigned short* xb    = (unsigned short*)(ws + 4096);        // 16 MB
  unsigned short* Wqkvb = (unsigned short*)(ws + 16781312);    // 6 MB [3072][1024]
  unsigned short* Wob   = (unsigned short*)(ws + 23072768);    // 2 MB
  unsigned short* qb    = (unsigned short*)(ws + 25169920);    // head-major, pre-scaled
  unsigned short* kb    = (unsigned short*)(ws + 41947136);    // head-major
  unsigned short* vhb   = (unsigned short*)(ws + 58724352);    // head-major V
  unsigned short* vtb   = (unsigned short*)(ws + 75501568);    // V^T [BH][64][L]
  unsigned short* ctxb  = vhb;                                 // reuse after transpose
  unsigned short* aob   = qb;                                  // reuse after attn

  const float QSCALE = 0.125f * 1.44269504f;  // softmax scale + log2(e) folded into Q

  cvt_all<<<12288, 256, 0, stream>>>(x, Wq, Wk, Wv, Wo, xb, Wqkvb, Wob);
  topk_idx<<<1, 256, 0, stream>>>(band, idxw);

  gemm_qkv<<<dim3(64, 24), 256, 0, stream>>>(xb, Wqkvb, bq, bk, bv,
                                             qb, kb, vhb, QSCALE);

  transpose_v<<<dim3(32, 64), 256, 0, stream>>>(vhb, vtb);

  attn4<<<dim3(16, 64), 256, 0, stream>>>(qb, kb, vtb, idxw, ctxb);

  gemm_wo<<<dim3(64, 8), 256, 0, stream>>>(ctxb, Wob, bo, aob);

  resid_ln<<<8192, 256, 0, stream>>>(x, aob, gamma, beta, out);
}